// Round 16
// baseline (3048.944 us; speedup 1.0000x reference)
//
#include <hip/hip_runtime.h>
#include <hip/hip_bf16.h>
#include <float.h>

#define K_NN 20
#define EPS 1e-5f
#define SLOPE 0.2f
constexpr int Bsz = 8;
constexpr int Npts = 2048;
constexpr int NQ = 8;            // layer-1 knn candidate-quadrant split
constexpr int BN = Bsz * Npts;   // 16384

typedef __attribute__((ext_vector_type(8))) short short8v;
typedef __attribute__((ext_vector_type(4))) float f32x4;

__device__ __forceinline__ float dot4(float4 a, float4 b) {
  return a.x*b.x + a.y*b.y + a.z*b.z + a.w*b.w;
}
// order-preserving float<->uint encoding for atomicMax pooling (exact, deterministic)
__device__ __forceinline__ unsigned encf(float f) {
  unsigned u = __float_as_uint(f);
  return (u & 0x80000000u) ? ~u : (u | 0x80000000u);
}
__device__ __forceinline__ float decf(unsigned e) {
  unsigned u = (e & 0x80000000u) ? (e & 0x7fffffffu) : ~e;
  return __uint_as_float(u);
}
// bf16 split helpers (RNE)
__device__ __forceinline__ unsigned short f2bf(float x) {
  unsigned u = __float_as_uint(x);
  unsigned r = (u + 0x7fffu + ((u >> 16) & 1u)) >> 16;
  return (unsigned short)r;
}
__device__ __forceinline__ float bf2f(unsigned short h) {
  return __uint_as_float((unsigned)h << 16);
}
__device__ __forceinline__ f32x4 mfma16(short8v a, short8v b, f32x4 c) {
  return __builtin_amdgcn_mfma_f32_16x16x32_bf16(a, b, c, 0, 0, 0);
}

// ---------------------------------------------------------------- sq of rows
template<int C>
__global__ __launch_bounds__(256) void sq_kernel(const float* __restrict__ xt,
                                                 float* __restrict__ sq) {
  int p = blockIdx.x * 256 + threadIdx.x;
  if (p >= BN) return;
  const float* r = xt + (size_t)p * C;
  float s = 0.f;
  if constexpr (C % 4 == 0) {
    for (int c4 = 0; c4 < C / 4; ++c4) { float4 v = *(const float4*)(r + c4 * 4); s += dot4(v, v); }
  } else {
    #pragma unroll
    for (int c = 0; c < C; ++c) { float v = r[c]; s += v * v; }
  }
  sq[p] = s;
}

// ------------------------------------------------- layer-1 knn partial top-k (C=3)
template<int C, int MT>
__global__ __launch_bounds__(256) void knn_part(const float* __restrict__ xt,
    const float* __restrict__ sq, float* __restrict__ pval, int* __restrict__ pidx) {
  constexpr int MQ = Npts / NQ;
  __shared__ __align__(16) float chk[MT][C];
  __shared__ float csq[MT];
  const int t = threadIdx.x, w = t >> 6, l = t & 63;
  const int rowblk = blockIdx.x / NQ;
  const int q = blockIdx.x - rowblk * NQ;
  const int p0 = rowblk * 256;
  const int b = p0 / Npts;
  const int myrow = p0 + w * 64 + l;

  float cr[C];
  #pragma unroll
  for (int c = 0; c < C; ++c) cr[c] = xt[(size_t)myrow * C + c];
  const float sqn = sq[myrow];

  float vals[K_NN]; int ids[K_NN];
  #pragma unroll
  for (int i = 0; i < K_NN; ++i) { vals[i] = -FLT_MAX; ids[i] = 0; }

  const int mbase = q * MQ;
  for (int m0 = mbase; m0 < mbase + MQ; m0 += MT) {
    __syncthreads();
    const float* s2 = xt + ((size_t)b * Npts + m0) * C;
    for (int e = t; e < MT * C; e += 256) chk[e / C][e - (e / C) * C] = s2[e];
    for (int e = t; e < MT; e += 256) csq[e] = sq[b * Npts + m0 + e];
    __syncthreads();
    for (int j = 0; j < MT; ++j) {
      float dt = 0.f;
      #pragma unroll
      for (int c = 0; c < C; ++c) dt += cr[c] * chk[j][c];
      float nd = 2.f * dt - sqn - csq[j];
      if (nd > vals[K_NN - 1]) {          // strict: ties keep earlier (lower) index
        vals[K_NN - 1] = nd; ids[K_NN - 1] = m0 + j;
        #pragma unroll
        for (int i = K_NN - 1; i >= 1; --i) {
          if (vals[i] > vals[i - 1]) {
            float tv = vals[i]; vals[i] = vals[i-1]; vals[i-1] = tv;
            int ti = ids[i]; ids[i] = ids[i-1]; ids[i-1] = ti;
          }
        }
      }
    }
  }
  size_t base = ((size_t)q * BN + myrow) * K_NN;
  #pragma unroll
  for (int i = 0; i < K_NN; ++i) { pval[base + i] = vals[i]; pidx[base + i] = ids[i]; }
}

// ------------------------------------------------- merge NQ sorted lists -> top-20
__global__ __launch_bounds__(256) void knn_merge(const float* __restrict__ pval,
    const int* __restrict__ pidx, int* __restrict__ idxout) {
  int p = blockIdx.x * 256 + threadIdx.x;
  if (p >= BN) return;
  float vals[K_NN]; int ids[K_NN];
  size_t base = (size_t)p * K_NN;
  #pragma unroll
  for (int i = 0; i < K_NN; ++i) { vals[i] = pval[base + i]; ids[i] = pidx[base + i]; }
  for (int q = 1; q < NQ; ++q) {
    size_t b2 = ((size_t)q * BN + p) * K_NN;
    #pragma unroll
    for (int i = 0; i < K_NN; ++i) {
      float v = pval[b2 + i];
      if (v <= vals[K_NN - 1]) break;
      int m = pidx[b2 + i];
      vals[K_NN - 1] = v; ids[K_NN - 1] = m;
      #pragma unroll
      for (int r = K_NN - 1; r >= 1; --r) {
        if (vals[r] > vals[r - 1]) {
          float tv = vals[r]; vals[r] = vals[r-1]; vals[r-1] = tv;
          int ti = ids[r]; ids[r] = ids[r-1]; ids[r-1] = ti;
        }
      }
    }
  }
  int* op = idxout + (size_t)p * K_NN;
  #pragma unroll
  for (int i = 0; i < K_NN; ++i) op[i] = ids[i];
}

// ------------------------------------------------- knn body (R10-proven compact scan)
// Block = 4 waves x 16 queries; wave wv scans candidate quadrant [wv*512,+512).
// MFMA (swapped operands) -> finished nd values to WAVE-PRIVATE LDS tile ->
// runtime-loop scan. 4 grp-lists merge via shfl; 4 wave-lists merge via LDS.
template<int C>
__device__ __forceinline__ void knn_body(
    const unsigned short* __restrict__ xh, const unsigned short* __restrict__ xl,
    const float* __restrict__ sq, int* __restrict__ idxout, int bid,
    float (*dist)[64][17], float (*svv)[16][K_NN], int (*sii)[16][K_NN]) {
  constexpr int KS = C / 32;
  constexpr int TPW = Npts / 64 / 4;       // candidate tiles per wave = 8
  const int b = bid >> 7, qt = bid & 127;
  const int q0 = qt * 16;
  const int t = threadIdx.x, wv = t >> 6, l = t & 63, l15 = l & 15, grp = l >> 4;
  const unsigned short* xbh = xh + (size_t)b * Npts * C;
  const unsigned short* xbl = xl + (size_t)b * Npts * C;
  const float* sqb = sq + b * Npts;
  const int qi = q0 + l15;

  short8v bh[KS], bl[KS];
  #pragma unroll
  for (int ks = 0; ks < KS; ++ks) {
    const size_t a = (size_t)qi * C + ks * 32 + grp * 8;
    bh[ks] = *(const short8v*)(xbh + a);
    bl[ks] = *(const short8v*)(xbl + a);
  }
  const float sqn = sqb[qi];

  float vals[K_NN]; int ids[K_NN];
  #pragma unroll
  for (int i = 0; i < K_NN; ++i) { vals[i] = -FLT_MAX; ids[i] = 0; }

  #pragma unroll 1
  for (int ti = 0; ti < TPW; ++ti) {
    const int m0 = (wv * TPW + ti) * 64;
    f32x4 acc[4];
    #pragma unroll
    for (int rt = 0; rt < 4; ++rt) acc[rt] = (f32x4){0.f, 0.f, 0.f, 0.f};
    #pragma unroll
    for (int ks = 0; ks < KS; ++ks) {
      #pragma unroll
      for (int rt = 0; rt < 4; ++rt) {
        const size_t aoff = (size_t)(m0 + rt * 16 + l15) * C + ks * 32 + grp * 8;
        const short8v a_h = *(const short8v*)(xbh + aoff);
        const short8v a_l = *(const short8v*)(xbl + aoff);
        acc[rt] = mfma16(a_h, bh[ks], acc[rt]);
        acc[rt] = mfma16(a_l, bh[ks], acc[rt]);
        acc[rt] = mfma16(a_h, bl[ks], acc[rt]);
      }
    }
    // finished nd values -> wave-private LDS (lane holds cands {m0+rt*16+grp*4+r})
    #pragma unroll
    for (int rt = 0; rt < 4; ++rt) {
      const int cb = m0 + rt * 16 + grp * 4;
      const float4 s4 = *(const float4*)(sqb + cb);
      const float sv[4] = {s4.x, s4.y, s4.z, s4.w};
      #pragma unroll
      for (int r = 0; r < 4; ++r) {
        const int cand = cb + r;
        float v = 2.f * acc[rt][r] - sqn - sv[r];
        if (cand == qi) v = 0.f;           // exact self-distance
        dist[wv][rt * 16 + grp * 4 + r][l15] = v;
      }
    }
    // same-wave LDS exchange: drain DS queue, forbid hoisting
    asm volatile("s_waitcnt lgkmcnt(0)" ::: "memory");
    __builtin_amdgcn_sched_barrier(0);
    // scan: lane (s=grp, q=l15) scans rows [grp*16, grp*16+16) for query qi
    #pragma unroll 1
    for (int j = 0; j < 16; ++j) {
      const float v = dist[wv][grp * 16 + j][l15];
      if (v > vals[K_NN - 1]) {            // strict: ties keep earlier index
        const int cand = m0 + grp * 16 + j;
        vals[K_NN - 1] = v; ids[K_NN - 1] = cand;
        #pragma unroll
        for (int i = K_NN - 1; i >= 1; --i) {
          if (vals[i] > vals[i - 1]) {
            float tv = vals[i]; vals[i] = vals[i-1]; vals[i-1] = tv;
            int ti2 = ids[i]; ids[i] = ids[i-1]; ids[i-1] = ti2;
          }
        }
      }
    }
  }

  // merge grp1..3 lists into grp0 (shfl; sources stay untouched)
  #pragma unroll
  for (int s2 = 1; s2 < 4; ++s2) {
    float ov[K_NN]; int oi[K_NN];
    #pragma unroll
    for (int i = 0; i < K_NN; ++i) {
      ov[i] = __shfl(vals[i], s2 * 16 + l15);
      oi[i] = __shfl(ids[i],  s2 * 16 + l15);
    }
    if (grp == 0) {
      #pragma unroll
      for (int i = 0; i < K_NN; ++i) {
        const float v = ov[i];
        if (v <= vals[K_NN - 1]) break;    // sorted source -> rest also fail
        vals[K_NN - 1] = v; ids[K_NN - 1] = oi[i];
        #pragma unroll
        for (int r = K_NN - 1; r >= 1; --r) {
          if (vals[r] > vals[r - 1]) {
            float tv = vals[r]; vals[r] = vals[r-1]; vals[r-1] = tv;
            int ti2 = ids[r]; ids[r] = ids[r-1]; ids[r-1] = ti2;
          }
        }
      }
    }
  }
  // cross-wave merge via LDS (wave order = ascending candidate quadrant)
  if (grp == 0) {
    #pragma unroll
    for (int i = 0; i < K_NN; ++i) { svv[wv][l15][i] = vals[i]; sii[wv][l15][i] = ids[i]; }
  }
  __syncthreads();
  if (t < 16) {                            // wave 0, lane t owns query q0+t
    #pragma unroll
    for (int s2 = 1; s2 < 4; ++s2) {
      #pragma unroll
      for (int i = 0; i < K_NN; ++i) {
        const float v = svv[s2][t][i];
        if (v <= vals[K_NN - 1]) break;
        vals[K_NN - 1] = v; ids[K_NN - 1] = sii[s2][t][i];
        #pragma unroll
        for (int r = K_NN - 1; r >= 1; --r) {
          if (vals[r] > vals[r - 1]) {
            float tv = vals[r]; vals[r] = vals[r-1]; vals[r-1] = tv;
            int ti2 = ids[r]; ids[r] = ids[r-1]; ids[r-1] = ti2;
          }
        }
      }
    }
    int* op = idxout + ((size_t)(b * Npts + q0 + t)) * K_NN;
    #pragma unroll
    for (int i = 0; i < K_NN; ++i) op[i] = ids[i];
  }
}

// ------------------------------------------------- zgemm body (Z = X * Wcat^T, split-3)
template<int C, int N2>
__device__ __forceinline__ void zgemm_body(
    const unsigned short* __restrict__ xh, const unsigned short* __restrict__ xl,
    const unsigned short* __restrict__ wh, const unsigned short* __restrict__ wl,
    float* __restrict__ Z, int r0, int bid) {
  constexpr int KS = C / 32;
  constexpr int CB = N2 / 64;
  const int nb = bid / CB, cb = bid - nb * CB;
  const int ln0 = nb * 64;
  const int t = threadIdx.x, l = t & 63, wv = t >> 6, l15 = l & 15, grp = l >> 4;
  const int col = cb * 64 + wv * 16 + l15;
  f32x4 acc[4];
  #pragma unroll
  for (int rt = 0; rt < 4; ++rt) acc[rt] = (f32x4){0.f, 0.f, 0.f, 0.f};
  #pragma unroll
  for (int ks = 0; ks < KS; ++ks) {
    const int krd = ks * 32 + grp * 8;
    const short8v bh = *(const short8v*)(wh + (size_t)col * C + krd);
    const short8v bl = *(const short8v*)(wl + (size_t)col * C + krd);
    #pragma unroll
    for (int rt = 0; rt < 4; ++rt) {
      const size_t arow = (size_t)(r0 + ln0 + rt * 16 + l15) * C + krd;
      const short8v a_h = *(const short8v*)(xh + arow);
      const short8v a_l = *(const short8v*)(xl + arow);
      acc[rt] = mfma16(a_h, bh, acc[rt]);
      acc[rt] = mfma16(a_l, bh, acc[rt]);
      acc[rt] = mfma16(a_h, bl, acc[rt]);
    }
  }
  #pragma unroll
  for (int rt = 0; rt < 4; ++rt)
    #pragma unroll
    for (int r = 0; r < 4; ++r)
      Z[(size_t)(ln0 + rt * 16 + grp * 4 + r) * N2 + col] = acc[rt][r];
}

// ------------------------------------------------- fused knn + zgemm (grid union)
// Blocks [0, KNNB) run the latency-bound knn scan; blocks [KNNB, ...) run the
// dense zgemm. Independent work (both read xh/xl only) -> zgemm fills the CU
// stall gaps of knn waves, and one kernel-launch gap disappears.
template<int C, int N2, int KNNB>
__global__ __launch_bounds__(256) void knn_zgemm(
    const unsigned short* __restrict__ xh, const unsigned short* __restrict__ xl,
    const float* __restrict__ sq, int* __restrict__ idxout,
    const unsigned short* __restrict__ wh, const unsigned short* __restrict__ wl,
    float* __restrict__ Z, int r0) {
  __shared__ float dist[4][64][17];
  __shared__ float svv[4][16][K_NN];
  __shared__ int   sii[4][16][K_NN];
  if ((int)blockIdx.x < KNNB) {
    knn_body<C>(xh, xl, sq, idxout, blockIdx.x, dist, svv, sii);
  } else {
    zgemm_body<C, N2>(xh, xl, wh, wl, Z, r0, blockIdx.x - KNNB);
  }
}

// ------------------------------------------------- standalone zgemm (L3 pass 1)
template<int C, int N2>
__global__ __launch_bounds__(256) void zgemm(
    const unsigned short* __restrict__ xh, const unsigned short* __restrict__ xl,
    const unsigned short* __restrict__ wh, const unsigned short* __restrict__ wl,
    float* __restrict__ Z, int r0) {
  zgemm_body<C, N2>(xh, xl, wh, wl, Z, r0, blockIdx.x);
}

// ------------------------------------------------- prep: [W_lo; W_hi-W_lo] bf16 split
template<int C, int O>
__global__ __launch_bounds__(256) void prep_w(const float* __restrict__ W,
    unsigned short* __restrict__ wh, unsigned short* __restrict__ wl) {
  int i = blockIdx.x * 256 + threadIdx.x;
  if (i >= 2 * O * C) return;
  int j = i / C, c = i - j * C;
  float v = (j < O) ? W[(size_t)j * 2 * C + c]
                    : (W[(size_t)(j - O) * 2 * C + C + c] - W[(size_t)(j - O) * 2 * C + c]);
  unsigned short h = f2bf(v);
  wh[i] = h; wl[i] = f2bf(v - bf2f(h));
}

// ------------------------------------------------- neighbor gather-reduce
// y_k = Z[nb_k][o] + Z[p][O+o]; emits per-point max/min (NC layout) + block stats.
template<int O, int NPP>
__global__ __launch_bounds__(256) void nbr_reduce(
    const float* __restrict__ Z, const int* __restrict__ idx,
    float* __restrict__ mx, float* __restrict__ mn,
    float* __restrict__ psum, float* __restrict__ psq, int r0) {
  constexpr int PPB = 256 / O;
  constexpr int O2 = 2 * O;
  const int t = threadIdx.x;
  const int o = t % O;
  const int sub = t / O;
  float ls = 0.f, lq = 0.f;
  for (int it = 0; it < NPP / PPB; ++it) {
    const int p = r0 + blockIdx.x * NPP + it * PPB + sub;
    const int bbase = (p >> 11) << 11;            // batch start (global row)
    const int* ip = idx + (size_t)p * K_NN;
    const float base = Z[(size_t)(p - r0) * O2 + O + o];
    float vmx = -FLT_MAX, vmn = FLT_MAX;
    #pragma unroll
    for (int k = 0; k < K_NN; ++k) {
      const int nbrow = bbase + ip[k] - r0;       // Z-local row
      const float y = Z[(size_t)nbrow * O2 + o] + base;
      ls += y; lq = fmaf(y, y, lq);
      vmx = fmaxf(vmx, y); vmn = fminf(vmn, y);
    }
    mx[(size_t)p * O + o] = vmx;
    mn[(size_t)p * O + o] = vmn;
  }
  if constexpr (PPB > 1) {
    __shared__ float s1[256], s2[256];
    s1[t] = ls; s2[t] = lq;
    __syncthreads();
    if (sub == 0) {
      psum[(size_t)blockIdx.x * O + o] = ls + s1[t + O];
      psq [(size_t)blockIdx.x * O + o] = lq + s2[t + O];
    }
  } else {
    psum[(size_t)blockIdx.x * O + o] = ls;
    psq [(size_t)blockIdx.x * O + o] = lq;
  }
}

// ------------------------------------------------- vector edge conv (layer 1, C=3)
template<int C, int O, int G, int NPG, int CPT>
__global__ __launch_bounds__(256) void edge_kernel(const float* __restrict__ xt,
    const int* __restrict__ idx, const float* __restrict__ W,
    float* __restrict__ mx, float* __restrict__ mn,
    float* __restrict__ psum, float* __restrict__ psq) {
  constexpr int WP = O / (64 * CPT);
  constexpr int TPB = 64 * WP * NPG;
  constexpr int PPG = G / NPG;
  static_assert(TPB == 256, "block must be 256 threads");
  __shared__ __align__(16) float pts[G][K_NN + 1][C];
  __shared__ int ids[G][K_NN + 1];
  __shared__ float shps[NPG][O];
  __shared__ float shpq[NPG][O];
  const int t = threadIdx.x;
  const int p0 = blockIdx.x * G;
  const int b = p0 / Npts;

  for (int e = t; e < G * (K_NN + 1); e += TPB) {
    int g = e / (K_NN + 1), j = e - g * (K_NN + 1);
    ids[g][j] = (j == 0) ? (p0 + g) : (b * Npts + idx[(size_t)(p0 + g) * K_NN + (j - 1)]);
  }
  __syncthreads();
  for (int e = t; e < G * (K_NN + 1) * C; e += TPB) {
    int g = e / ((K_NN + 1) * C), rem = e - g * ((K_NN + 1) * C);
    int j = rem / C, c = rem - j * C;
    pts[g][j][c] = xt[(size_t)ids[g][j] * C + c];
  }
  __syncthreads();

  const int w = t >> 6, l = t & 63;
  const int pg = w / WP, wp = w - pg * WP;
  const int o0 = wp * 64 + l;
  float ls0 = 0.f, lq0 = 0.f;

  for (int it = 0; it < PPG; ++it) {
    const int g = pg * PPG + it;
    float yk0[K_NN];
    float u0 = 0.f, v0 = 0.f;
    #pragma unroll
    for (int k = 0; k < K_NN; ++k) yk0[k] = 0.f;
    const float* W0 = W + (size_t)o0 * (2 * C);
    #pragma unroll
    for (int c = 0; c < C; ++c) {
      const float wl = W0[c], whv = W0[C + c], ccv = pts[g][0][c];
      u0 += wl * ccv; v0 += whv * ccv;
      #pragma unroll
      for (int k = 0; k < K_NN; ++k) yk0[k] += wl * pts[g][k + 1][c];
    }
    const int n = p0 + g - b * Npts;
    const size_t obase = ((size_t)b * Npts + n) * O;
    const float base = v0 - u0;
    float vmx = -FLT_MAX, vmn = FLT_MAX;
    #pragma unroll
    for (int k = 0; k < K_NN; ++k) {
      float y = yk0[k] + base;
      ls0 += y; lq0 += y * y;
      vmx = fmaxf(vmx, y); vmn = fminf(vmn, y);
    }
    mx[obase + o0] = vmx; mn[obase + o0] = vmn;
  }

  shps[pg][o0] = ls0; shpq[pg][o0] = lq0;
  __syncthreads();
  if (t < O) {
    float s = 0.f, qq = 0.f;
    #pragma unroll
    for (int i = 0; i < NPG; ++i) { s += shps[i][t]; qq += shpq[i][t]; }
    psum[(size_t)blockIdx.x * O + t] = s;
    psq [(size_t)blockIdx.x * O + t] = qq;
  }
}

// ------------------------------------------------- two-stage BN stats
template<int O, int NBLK>
__global__ __launch_bounds__(256) void stats_part(const float* __restrict__ psum,
    const float* __restrict__ psq, double* __restrict__ pp, double* __restrict__ pq) {
  constexpr int NS = 16;
  constexpr int SL = NBLK / NS;
  const int l = threadIdx.x & 63, w = threadIdx.x >> 6;
  const int os = blockIdx.x % (O / 64), sl = blockIdx.x / (O / 64);
  const int o = os * 64 + l;
  double s = 0.0, ss = 0.0;
  for (int i = sl * SL + w; i < (sl + 1) * SL; i += 4) {
    s  += (double)psum[(size_t)i * O + o];
    ss += (double)psq [(size_t)i * O + o];
  }
  __shared__ double sh[2][4][64];
  sh[0][w][l] = s; sh[1][w][l] = ss;
  __syncthreads();
  if (w == 0) {
    s  = sh[0][0][l] + sh[0][1][l] + sh[0][2][l] + sh[0][3][l];
    ss = sh[1][0][l] + sh[1][1][l] + sh[1][2][l] + sh[1][3][l];
    pp[(size_t)sl * O + o] = s;
    pq[(size_t)sl * O + o] = ss;
  }
}

template<int O>
__global__ __launch_bounds__(64) void stats_final(const double* __restrict__ pp,
    const double* __restrict__ pq,
    const float* __restrict__ gamma, const float* __restrict__ beta,
    float* __restrict__ scale, float* __restrict__ bias) {
  const int o = blockIdx.x * 64 + threadIdx.x;
  double s = 0.0, ss = 0.0;
  #pragma unroll
  for (int sl = 0; sl < 16; ++sl) { s += pp[(size_t)sl * O + o]; ss += pq[(size_t)sl * O + o]; }
  double cnt = (double)Bsz * Npts * K_NN;
  double m = s / cnt;
  double var = ss / cnt - m * m;
  float g = gamma[o];
  float sc = g * rsqrtf((float)var + EPS);
  scale[o] = sc;
  bias[o] = beta[o] - (float)m * sc;
}

// ------------------------------------------------- reset pooled accumulators
__global__ __launch_bounds__(256) void reset_pool(unsigned* __restrict__ pooled) {
  int i = blockIdx.x * 256 + threadIdx.x;
  if (i < Bsz * 448) pooled[i] = 0u;   // 0 < encf(f) for all finite f
}

// ------------------------------------------------- normalize + lrelu + pool + bf16 split
template<int O, int COFF, bool WNC>
__global__ __launch_bounds__(256) void apply_kernel(const float* __restrict__ mx,
    const float* __restrict__ mn, const float* __restrict__ scale,
    const float* __restrict__ bias, float* __restrict__ xnc,
    unsigned short* __restrict__ xh, unsigned short* __restrict__ xl,
    unsigned* __restrict__ pooled) {
  constexpr int OT = O / 64;
  constexpr int NCH = Npts / 256;
  const int bid = blockIdx.x;
  const int nchunk = bid % NCH;
  const int ot = (bid / NCH) % OT;
  const int b = bid / (NCH * OT);
  const int l = threadIdx.x & 63, w = threadIdx.x >> 6;
  const int o = ot * 64 + l;
  const float sc = scale[o], bs = bias[o];
  const bool pos = (sc >= 0.f);
  float vmax = -FLT_MAX;
  const int n0 = nchunk * 256;
  for (int i = 0; i < 64; ++i) {
    int n = n0 + w + i * 4;
    size_t ix = ((size_t)b * Npts + n) * O + o;
    float raw = pos ? mx[ix] : mn[ix];   // max for +scale, min for -scale
    float y = raw * sc + bs;
    y = (y >= 0.f) ? y : SLOPE * y;
    if constexpr (WNC) {
      xnc[ix] = y;
      unsigned short h = f2bf(y);
      xh[ix] = h;
      xl[ix] = f2bf(y - bf2f(h));
    }
    vmax = fmaxf(vmax, y);
  }
  __shared__ float sh[4][64];
  sh[w][l] = vmax;
  __syncthreads();
  if (w == 0) {
    float m = fmaxf(fmaxf(sh[0][l], sh[1][l]), fmaxf(sh[2][l], sh[3][l]));
    atomicMax(pooled + b * 448 + COFF + o, encf(m));
  }
}

// ------------------------------------------------- FC layers
template<int CIN, bool LRELU, bool DECODE>
__global__ __launch_bounds__(64) void fc_kernel(const void* __restrict__ inv,
    const float* __restrict__ Wt, float* __restrict__ out, int JO) {
  int j = blockIdx.x;
  const float* wr = Wt + (size_t)j * CIN;
  float acc[Bsz];
  #pragma unroll
  for (int b = 0; b < Bsz; ++b) acc[b] = 0.f;
  for (int c = threadIdx.x; c < CIN; c += 64) {
    float wv = wr[c];
    #pragma unroll
    for (int b = 0; b < Bsz; ++b) {
      float x;
      if constexpr (DECODE) x = decf(((const unsigned*)inv)[b * CIN + c]);
      else                  x = ((const float*)inv)[b * CIN + c];
      acc[b] += x * wv;
    }
  }
  #pragma unroll
  for (int b = 0; b < Bsz; ++b) {
    float v = acc[b];
    #pragma unroll
    for (int w = 32; w > 0; w >>= 1) v += __shfl_down(v, w);
    if (threadIdx.x == 0) {
      if (LRELU) v = (v >= 0.f) ? v : SLOPE * v;
      out[b * JO + j] = v;
    }
  }
}

// ================================================================ launch
extern "C" void kernel_launch(void* const* d_in, const int* in_sizes, int n_in,
                              void* d_out, int out_size, void* d_ws, size_t ws_size,
                              hipStream_t stream) {
  const float* x   = (const float*)d_in[0];
  const float* W1  = (const float*)d_in[1];
  const float* g1  = (const float*)d_in[2];
  const float* b1  = (const float*)d_in[3];
  const float* W2  = (const float*)d_in[4];
  const float* g2  = (const float*)d_in[5];
  const float* b2  = (const float*)d_in[6];
  const float* W3  = (const float*)d_in[7];
  const float* g3  = (const float*)d_in[8];
  const float* b3  = (const float*)d_in[9];
  const float* L1  = (const float*)d_in[10];
  const float* L2  = (const float*)d_in[11];
  float* out = (float*)d_out;

  float* ws = (float*)d_ws;
  size_t off = 0;
  float* sq    = ws + off; off += BN;
  int*   idxb  = (int*)(ws + off); off += (size_t)BN * K_NN;
  float* mx    = ws + off; off += (size_t)BN * 256;
  float* mn    = ws + off; off += (size_t)BN * 256;
  float* Z     = ws + off; off += (size_t)BN * 256;          // 16.8MB (2-pass for L3)
  float* psum  = ws + off; off += (size_t)2048 * 256;
  float* psq   = ws + off; off += (size_t)2048 * 256;
  off = (off + 1) & ~(size_t)1;   // 8B align for doubles
  double* pp   = (double*)(ws + off); off += 16 * 256 * 2;
  double* pq   = (double*)(ws + off); off += 16 * 256 * 2;
  float* scale = ws + off; off += 256;
  float* bias  = ws + off; off += 256;
  float* x1nc  = ws + off; off += (size_t)BN * 64;
  float* x2nc  = ws + off; off += (size_t)BN * 128;
  unsigned short* xh1 = (unsigned short*)(ws + off); off += (size_t)BN * 64 / 2;
  unsigned short* xl1 = (unsigned short*)(ws + off); off += (size_t)BN * 64 / 2;
  unsigned short* xh2 = (unsigned short*)(ws + off); off += (size_t)BN * 128 / 2;
  unsigned short* xl2 = (unsigned short*)(ws + off); off += (size_t)BN * 128 / 2;
  unsigned* pooled = (unsigned*)(ws + off); off += Bsz * 448;
  float* h     = ws + off; off += Bsz * 1024;
  unsigned short* wch2 = (unsigned short*)(ws + off); off += 256 * 64 / 2;
  unsigned short* wcl2 = (unsigned short*)(ws + off); off += 256 * 64 / 2;
  unsigned short* wch3 = (unsigned short*)(ws + off); off += 512 * 128 / 2;
  unsigned short* wcl3 = (unsigned short*)(ws + off); off += 512 * 128 / 2;
  // layer-1 knn partial lists overlay mx/mn (disjoint lifetimes)
  float* pval = mx;
  int*   pidx = (int*)mn;

  reset_pool<<<14, 256, 0, stream>>>(pooled);
  prep_w<64, 128><<<(2 * 128 * 64 + 255) / 256, 256, 0, stream>>>(W2, wch2, wcl2);
  prep_w<128, 256><<<(2 * 256 * 128 + 255) / 256, 256, 0, stream>>>(W3, wch3, wcl3);

  // ---- edge block 1: C=3 -> O=64 (fp32 vector knn + conv)
  sq_kernel<3><<<64, 256, 0, stream>>>(x, sq);
  knn_part<3, 64><<<(BN / 256) * NQ, 256, 0, stream>>>(x, sq, pval, pidx);
  knn_merge<<<64, 256, 0, stream>>>(pval, pidx, idxb);
  edge_kernel<3, 64, 16, 4, 1><<<BN / 16, 256, 0, stream>>>(x, idxb, W1, mx, mn, psum, psq);
  stats_part<64, 1024><<<16, 256, 0, stream>>>(psum, psq, pp, pq);
  stats_final<64><<<1, 64, 0, stream>>>(pp, pq, g1, b1, scale, bias);
  apply_kernel<64, 0, true><<<64, 256, 0, stream>>>(mx, mn, scale, bias, x1nc, xh1, xl1, pooled);

  // ---- edge block 2: C=64 -> O=128 (fused knn+zgemm, then gather-reduce)
  sq_kernel<64><<<64, 256, 0, stream>>>(x1nc, sq);
  knn_zgemm<64, 256, Bsz * 128><<<Bsz * 128 + (BN / 64) * 4, 256, 0, stream>>>(
      xh1, xl1, sq, idxb, wch2, wcl2, Z, 0);
  nbr_reduce<128, 16><<<BN / 16, 256, 0, stream>>>(Z, idxb, mx, mn, psum, psq, 0);
  stats_part<128, 1024><<<32, 256, 0, stream>>>(psum, psq, pp, pq);
  stats_final<128><<<2, 64, 0, stream>>>(pp, pq, g2, b2, scale, bias);
  apply_kernel<128, 64, true><<<128, 256, 0, stream>>>(mx, mn, scale, bias, x2nc, xh2, xl2, pooled);

  // ---- edge block 3: C=128 -> O=256 (fused knn+zgemm pass0, reduce, pass1)
  sq_kernel<128><<<64, 256, 0, stream>>>(x2nc, sq);
  knn_zgemm<128, 512, Bsz * 128><<<Bsz * 128 + (BN / 2 / 64) * 8, 256, 0, stream>>>(
      xh2, xl2, sq, idxb, wch3, wcl3, Z, 0);
  nbr_reduce<256, 8><<<BN / 2 / 8, 256, 0, stream>>>(Z, idxb, mx, mn, psum, psq, 0);
  zgemm<128, 512><<<(BN / 2 / 64) * 8, 256, 0, stream>>>(xh2, xl2, wch3, wcl3, Z, BN / 2);
  nbr_reduce<256, 8><<<BN / 2 / 8, 256, 0, stream>>>(Z, idxb, mx, mn,
      psum + (size_t)1024 * 256, psq + (size_t)1024 * 256, BN / 2);
  stats_part<256, 2048><<<64, 256, 0, stream>>>(psum, psq, pp, pq);
  stats_final<256><<<4, 64, 0, stream>>>(pp, pq, g3, b3, scale, bias);
  apply_kernel<256, 192, false><<<256, 256, 0, stream>>>(mx, mn, scale, bias, nullptr, nullptr, nullptr, pooled);

  // ---- head
  fc_kernel<448, true, true><<<1024, 64, 0, stream>>>(pooled, L1, h, 1024);
  fc_kernel<1024, false, false><<<2500, 64, 0, stream>>>(h, L2, out, 2500);
}

// Round 17
// 1008.856 us; speedup vs baseline: 3.0222x; 3.0222x over previous
//
#include <hip/hip_runtime.h>
#include <hip/hip_bf16.h>
#include <float.h>

#define K_NN 20
#define EPS 1e-5f
#define SLOPE 0.2f
constexpr int Bsz = 8;
constexpr int Npts = 2048;
constexpr int NQ = 8;            // layer-1 knn candidate-quadrant split
constexpr int BN = Bsz * Npts;   // 16384

typedef __attribute__((ext_vector_type(8))) short short8v;
typedef __attribute__((ext_vector_type(4))) float f32x4;

__device__ __forceinline__ float dot4(float4 a, float4 b) {
  return a.x*b.x + a.y*b.y + a.z*b.z + a.w*b.w;
}
// order-preserving float<->uint encoding for atomicMax pooling (exact, deterministic)
__device__ __forceinline__ unsigned encf(float f) {
  unsigned u = __float_as_uint(f);
  return (u & 0x80000000u) ? ~u : (u | 0x80000000u);
}
__device__ __forceinline__ float decf(unsigned e) {
  unsigned u = (e & 0x80000000u) ? (e & 0x7fffffffu) : ~e;
  return __uint_as_float(u);
}
// bf16 split helpers (RNE)
__device__ __forceinline__ unsigned short f2bf(float x) {
  unsigned u = __float_as_uint(x);
  unsigned r = (u + 0x7fffu + ((u >> 16) & 1u)) >> 16;
  return (unsigned short)r;
}
__device__ __forceinline__ float bf2f(unsigned short h) {
  return __uint_as_float((unsigned)h << 16);
}
__device__ __forceinline__ f32x4 mfma16(short8v a, short8v b, f32x4 c) {
  return __builtin_amdgcn_mfma_f32_16x16x32_bf16(a, b, c, 0, 0, 0);
}

// ---------------------------------------------------------------- sq of rows
template<int C>
__global__ __launch_bounds__(256) void sq_kernel(const float* __restrict__ xt,
                                                 float* __restrict__ sq) {
  int p = blockIdx.x * 256 + threadIdx.x;
  if (p >= BN) return;
  const float* r = xt + (size_t)p * C;
  float s = 0.f;
  if constexpr (C % 4 == 0) {
    for (int c4 = 0; c4 < C / 4; ++c4) { float4 v = *(const float4*)(r + c4 * 4); s += dot4(v, v); }
  } else {
    #pragma unroll
    for (int c = 0; c < C; ++c) { float v = r[c]; s += v * v; }
  }
  sq[p] = s;
}

// ------------------------------------------------- layer-1 knn partial top-k (C=3)
template<int C, int MT>
__global__ __launch_bounds__(256) void knn_part(const float* __restrict__ xt,
    const float* __restrict__ sq, float* __restrict__ pval, int* __restrict__ pidx) {
  constexpr int MQ = Npts / NQ;
  __shared__ __align__(16) float chk[MT][C];
  __shared__ float csq[MT];
  const int t = threadIdx.x, w = t >> 6, l = t & 63;
  const int rowblk = blockIdx.x / NQ;
  const int q = blockIdx.x - rowblk * NQ;
  const int p0 = rowblk * 256;
  const int b = p0 / Npts;
  const int myrow = p0 + w * 64 + l;

  float cr[C];
  #pragma unroll
  for (int c = 0; c < C; ++c) cr[c] = xt[(size_t)myrow * C + c];
  const float sqn = sq[myrow];

  float vals[K_NN]; int ids[K_NN];
  #pragma unroll
  for (int i = 0; i < K_NN; ++i) { vals[i] = -FLT_MAX; ids[i] = 0; }

  const int mbase = q * MQ;
  for (int m0 = mbase; m0 < mbase + MQ; m0 += MT) {
    __syncthreads();
    const float* s2 = xt + ((size_t)b * Npts + m0) * C;
    for (int e = t; e < MT * C; e += 256) chk[e / C][e - (e / C) * C] = s2[e];
    for (int e = t; e < MT; e += 256) csq[e] = sq[b * Npts + m0 + e];
    __syncthreads();
    for (int j = 0; j < MT; ++j) {
      float dt = 0.f;
      #pragma unroll
      for (int c = 0; c < C; ++c) dt += cr[c] * chk[j][c];
      float nd = 2.f * dt - sqn - csq[j];
      if (nd > vals[K_NN - 1]) {          // strict: ties keep earlier (lower) index
        vals[K_NN - 1] = nd; ids[K_NN - 1] = m0 + j;
        #pragma unroll
        for (int i = K_NN - 1; i >= 1; --i) {
          if (vals[i] > vals[i - 1]) {
            float tv = vals[i]; vals[i] = vals[i-1]; vals[i-1] = tv;
            int ti = ids[i]; ids[i] = ids[i-1]; ids[i-1] = ti;
          }
        }
      }
    }
  }
  size_t base = ((size_t)q * BN + myrow) * K_NN;
  #pragma unroll
  for (int i = 0; i < K_NN; ++i) { pval[base + i] = vals[i]; pidx[base + i] = ids[i]; }
}

// ------------------------------------------------- merge NQ sorted lists -> top-20
__global__ __launch_bounds__(256) void knn_merge(const float* __restrict__ pval,
    const int* __restrict__ pidx, int* __restrict__ idxout) {
  int p = blockIdx.x * 256 + threadIdx.x;
  if (p >= BN) return;
  float vals[K_NN]; int ids[K_NN];
  size_t base = (size_t)p * K_NN;
  #pragma unroll
  for (int i = 0; i < K_NN; ++i) { vals[i] = pval[base + i]; ids[i] = pidx[base + i]; }
  for (int q = 1; q < NQ; ++q) {
    size_t b2 = ((size_t)q * BN + p) * K_NN;
    #pragma unroll
    for (int i = 0; i < K_NN; ++i) {
      float v = pval[b2 + i];
      if (v <= vals[K_NN - 1]) break;
      int m = pidx[b2 + i];
      vals[K_NN - 1] = v; ids[K_NN - 1] = m;
      #pragma unroll
      for (int r = K_NN - 1; r >= 1; --r) {
        if (vals[r] > vals[r - 1]) {
          float tv = vals[r]; vals[r] = vals[r-1]; vals[r-1] = tv;
          int ti = ids[r]; ids[r] = ids[r-1]; ids[r-1] = ti;
        }
      }
    }
  }
  int* op = idxout + (size_t)p * K_NN;
  #pragma unroll
  for (int i = 0; i < K_NN; ++i) op[i] = ids[i];
}

// ------------------------------------------------- fused MFMA knn, compact-code scan
// Block = 4 waves x 16 queries; wave wv scans candidate quadrant [wv*512,+512).
// MFMA (swapped operands) -> finished nd values to WAVE-PRIVATE LDS tile ->
// runtime-loop scan (small code, I$-resident). 4 grp-lists merge via shfl;
// 4 wave-lists merge via LDS in wave 0. Insertion chains fully unrolled, no
// data-dependent break inside (R8 lesson).
template<int C>
__global__ __launch_bounds__(256) void knn_fused(
    const unsigned short* __restrict__ xh, const unsigned short* __restrict__ xl,
    const float* __restrict__ sq, int* __restrict__ idxout) {
  constexpr int KS = C / 32;
  constexpr int TPW = Npts / 64 / 4;       // candidate tiles per wave = 8
  __shared__ float dist[4][64][17];        // wave-private nd tile (pad 17: ~2-way banks)
  __shared__ float svv[4][16][K_NN];
  __shared__ int   sii[4][16][K_NN];
  const int b = blockIdx.x >> 7, qt = blockIdx.x & 127;
  const int q0 = qt * 16;
  const int t = threadIdx.x, wv = t >> 6, l = t & 63, l15 = l & 15, grp = l >> 4;
  const unsigned short* xbh = xh + (size_t)b * Npts * C;
  const unsigned short* xbl = xl + (size_t)b * Npts * C;
  const float* sqb = sq + b * Npts;
  const int qi = q0 + l15;

  short8v bh[KS], bl[KS];
  #pragma unroll
  for (int ks = 0; ks < KS; ++ks) {
    const size_t a = (size_t)qi * C + ks * 32 + grp * 8;
    bh[ks] = *(const short8v*)(xbh + a);
    bl[ks] = *(const short8v*)(xbl + a);
  }
  const float sqn = sqb[qi];

  float vals[K_NN]; int ids[K_NN];
  #pragma unroll
  for (int i = 0; i < K_NN; ++i) { vals[i] = -FLT_MAX; ids[i] = 0; }

  #pragma unroll 1
  for (int ti = 0; ti < TPW; ++ti) {
    const int m0 = (wv * TPW + ti) * 64;
    f32x4 acc[4];
    #pragma unroll
    for (int rt = 0; rt < 4; ++rt) acc[rt] = (f32x4){0.f, 0.f, 0.f, 0.f};
    #pragma unroll
    for (int ks = 0; ks < KS; ++ks) {
      #pragma unroll
      for (int rt = 0; rt < 4; ++rt) {
        const size_t aoff = (size_t)(m0 + rt * 16 + l15) * C + ks * 32 + grp * 8;
        const short8v a_h = *(const short8v*)(xbh + aoff);
        const short8v a_l = *(const short8v*)(xbl + aoff);
        acc[rt] = mfma16(a_h, bh[ks], acc[rt]);
        acc[rt] = mfma16(a_l, bh[ks], acc[rt]);
        acc[rt] = mfma16(a_h, bl[ks], acc[rt]);
      }
    }
    // finished nd values -> wave-private LDS (lane holds cands {m0+rt*16+grp*4+r} for query qi)
    #pragma unroll
    for (int rt = 0; rt < 4; ++rt) {
      const int cb = m0 + rt * 16 + grp * 4;
      const float4 s4 = *(const float4*)(sqb + cb);
      const float sv[4] = {s4.x, s4.y, s4.z, s4.w};
      #pragma unroll
      for (int r = 0; r < 4; ++r) {
        const int cand = cb + r;
        float v = 2.f * acc[rt][r] - sqn - sv[r];
        if (cand == qi) v = 0.f;           // exact self-distance
        dist[wv][rt * 16 + grp * 4 + r][l15] = v;
      }
    }
    // same-wave LDS exchange: drain DS queue, forbid hoisting
    asm volatile("s_waitcnt lgkmcnt(0)" ::: "memory");
    __builtin_amdgcn_sched_barrier(0);
    // scan: lane (s=grp, q=l15) scans rows [grp*16, grp*16+16) for query qi
    #pragma unroll 1
    for (int j = 0; j < 16; ++j) {
      const float v = dist[wv][grp * 16 + j][l15];
      if (v > vals[K_NN - 1]) {            // strict: ties keep earlier index
        const int cand = m0 + grp * 16 + j;
        vals[K_NN - 1] = v; ids[K_NN - 1] = cand;
        #pragma unroll
        for (int i = K_NN - 1; i >= 1; --i) {
          if (vals[i] > vals[i - 1]) {
            float tv = vals[i]; vals[i] = vals[i-1]; vals[i-1] = tv;
            int ti2 = ids[i]; ids[i] = ids[i-1]; ids[i-1] = ti2;
          }
        }
      }
    }
  }

  // merge grp1..3 lists into grp0 (shfl; sources stay untouched)
  #pragma unroll
  for (int s2 = 1; s2 < 4; ++s2) {
    float ov[K_NN]; int oi[K_NN];
    #pragma unroll
    for (int i = 0; i < K_NN; ++i) {
      ov[i] = __shfl(vals[i], s2 * 16 + l15);
      oi[i] = __shfl(ids[i],  s2 * 16 + l15);
    }
    if (grp == 0) {
      #pragma unroll
      for (int i = 0; i < K_NN; ++i) {
        const float v = ov[i];
        if (v <= vals[K_NN - 1]) break;    // sorted source -> rest also fail
        vals[K_NN - 1] = v; ids[K_NN - 1] = oi[i];
        #pragma unroll
        for (int r = K_NN - 1; r >= 1; --r) {
          if (vals[r] > vals[r - 1]) {
            float tv = vals[r]; vals[r] = vals[r-1]; vals[r-1] = tv;
            int ti2 = ids[r]; ids[r] = ids[r-1]; ids[r-1] = ti2;
          }
        }
      }
    }
  }
  // cross-wave merge via LDS (wave order = ascending candidate quadrant)
  if (grp == 0) {
    #pragma unroll
    for (int i = 0; i < K_NN; ++i) { svv[wv][l15][i] = vals[i]; sii[wv][l15][i] = ids[i]; }
  }
  __syncthreads();
  if (t < 16) {                            // wave 0, lane t owns query q0+t
    #pragma unroll
    for (int s2 = 1; s2 < 4; ++s2) {
      #pragma unroll
      for (int i = 0; i < K_NN; ++i) {
        const float v = svv[s2][t][i];
        if (v <= vals[K_NN - 1]) break;
        vals[K_NN - 1] = v; ids[K_NN - 1] = sii[s2][t][i];
        #pragma unroll
        for (int r = K_NN - 1; r >= 1; --r) {
          if (vals[r] > vals[r - 1]) {
            float tv = vals[r]; vals[r] = vals[r-1]; vals[r-1] = tv;
            int ti2 = ids[r]; ids[r] = ids[r-1]; ids[r-1] = ti2;
          }
        }
      }
    }
    int* op = idxout + ((size_t)(b * Npts + q0 + t)) * K_NN;
    #pragma unroll
    for (int i = 0; i < K_NN; ++i) op[i] = ids[i];
  }
}

// ------------------------------------------------- prep: [W_lo; W_hi-W_lo] bf16 split
template<int C, int O>
__global__ __launch_bounds__(256) void prep_w(const float* __restrict__ W,
    unsigned short* __restrict__ wh, unsigned short* __restrict__ wl) {
  int i = blockIdx.x * 256 + threadIdx.x;
  if (i >= 2 * O * C) return;
  int j = i / C, c = i - j * C;
  float v = (j < O) ? W[(size_t)j * 2 * C + c]
                    : (W[(size_t)(j - O) * 2 * C + C + c] - W[(size_t)(j - O) * 2 * C + c]);
  unsigned short h = f2bf(v);
  wh[i] = h; wl[i] = f2bf(v - bf2f(h));
}

// ------------------------------------------------- dense GEMM Z = X * Wcat^T (split-3)
// Z[BN][N2], cols 0..O-1 = W_lo part (z), cols O..2O-1 = D part (base).
template<int C, int N2>
__global__ __launch_bounds__(256) void zgemm(
    const unsigned short* __restrict__ xh, const unsigned short* __restrict__ xl,
    const unsigned short* __restrict__ wh, const unsigned short* __restrict__ wl,
    float* __restrict__ Z, int r0) {
  constexpr int KS = C / 32;
  constexpr int CB = N2 / 64;
  const int nb = blockIdx.x / CB, cb = blockIdx.x - nb * CB;
  const int ln0 = nb * 64;
  const int t = threadIdx.x, l = t & 63, wv = t >> 6, l15 = l & 15, grp = l >> 4;
  const int col = cb * 64 + wv * 16 + l15;
  f32x4 acc[4];
  #pragma unroll
  for (int rt = 0; rt < 4; ++rt) acc[rt] = (f32x4){0.f, 0.f, 0.f, 0.f};
  #pragma unroll
  for (int ks = 0; ks < KS; ++ks) {
    const int krd = ks * 32 + grp * 8;
    const short8v bh = *(const short8v*)(wh + (size_t)col * C + krd);
    const short8v bl = *(const short8v*)(wl + (size_t)col * C + krd);
    #pragma unroll
    for (int rt = 0; rt < 4; ++rt) {
      const size_t arow = (size_t)(r0 + ln0 + rt * 16 + l15) * C + krd;
      const short8v a_h = *(const short8v*)(xh + arow);
      const short8v a_l = *(const short8v*)(xl + arow);
      acc[rt] = mfma16(a_h, bh, acc[rt]);
      acc[rt] = mfma16(a_l, bh, acc[rt]);
      acc[rt] = mfma16(a_h, bl, acc[rt]);
    }
  }
  #pragma unroll
  for (int rt = 0; rt < 4; ++rt)
    #pragma unroll
    for (int r = 0; r < 4; ++r)
      Z[(size_t)(ln0 + rt * 16 + grp * 4 + r) * N2 + col] = acc[rt][r];
}

// ------------------------------------------------- neighbor gather-reduce
// y_k = Z[nb_k][o] + Z[p][O+o]; emits per-point max/min (NC layout) + block stats.
template<int O, int NPP>
__global__ __launch_bounds__(256) void nbr_reduce(
    const float* __restrict__ Z, const int* __restrict__ idx,
    float* __restrict__ mx, float* __restrict__ mn,
    float* __restrict__ psum, float* __restrict__ psq, int r0) {
  constexpr int PPB = 256 / O;
  constexpr int O2 = 2 * O;
  const int t = threadIdx.x;
  const int o = t % O;
  const int sub = t / O;
  float ls = 0.f, lq = 0.f;
  for (int it = 0; it < NPP / PPB; ++it) {
    const int p = r0 + blockIdx.x * NPP + it * PPB + sub;
    const int bbase = (p >> 11) << 11;            // batch start (global row)
    const int* ip = idx + (size_t)p * K_NN;
    const float base = Z[(size_t)(p - r0) * O2 + O + o];
    float vmx = -FLT_MAX, vmn = FLT_MAX;
    #pragma unroll
    for (int k = 0; k < K_NN; ++k) {
      const int nbrow = bbase + ip[k] - r0;       // Z-local row
      const float y = Z[(size_t)nbrow * O2 + o] + base;
      ls += y; lq = fmaf(y, y, lq);
      vmx = fmaxf(vmx, y); vmn = fminf(vmn, y);
    }
    mx[(size_t)p * O + o] = vmx;
    mn[(size_t)p * O + o] = vmn;
  }
  if constexpr (PPB > 1) {
    __shared__ float s1[256], s2[256];
    s1[t] = ls; s2[t] = lq;
    __syncthreads();
    if (sub == 0) {
      psum[(size_t)blockIdx.x * O + o] = ls + s1[t + O];
      psq [(size_t)blockIdx.x * O + o] = lq + s2[t + O];
    }
  } else {
    psum[(size_t)blockIdx.x * O + o] = ls;
    psq [(size_t)blockIdx.x * O + o] = lq;
  }
}

// ------------------------------------------------- vector edge conv (layer 1, C=3)
template<int C, int O, int G, int NPG, int CPT>
__global__ __launch_bounds__(256) void edge_kernel(const float* __restrict__ xt,
    const int* __restrict__ idx, const float* __restrict__ W,
    float* __restrict__ mx, float* __restrict__ mn,
    float* __restrict__ psum, float* __restrict__ psq) {
  constexpr int WP = O / (64 * CPT);
  constexpr int TPB = 64 * WP * NPG;
  constexpr int PPG = G / NPG;
  static_assert(TPB == 256, "block must be 256 threads");
  __shared__ __align__(16) float pts[G][K_NN + 1][C];
  __shared__ int ids[G][K_NN + 1];
  __shared__ float shps[NPG][O];
  __shared__ float shpq[NPG][O];
  const int t = threadIdx.x;
  const int p0 = blockIdx.x * G;
  const int b = p0 / Npts;

  for (int e = t; e < G * (K_NN + 1); e += TPB) {
    int g = e / (K_NN + 1), j = e - g * (K_NN + 1);
    ids[g][j] = (j == 0) ? (p0 + g) : (b * Npts + idx[(size_t)(p0 + g) * K_NN + (j - 1)]);
  }
  __syncthreads();
  for (int e = t; e < G * (K_NN + 1) * C; e += TPB) {
    int g = e / ((K_NN + 1) * C), rem = e - g * ((K_NN + 1) * C);
    int j = rem / C, c = rem - j * C;
    pts[g][j][c] = xt[(size_t)ids[g][j] * C + c];
  }
  __syncthreads();

  const int w = t >> 6, l = t & 63;
  const int pg = w / WP, wp = w - pg * WP;
  const int o0 = wp * 64 + l;
  float ls0 = 0.f, lq0 = 0.f;

  for (int it = 0; it < PPG; ++it) {
    const int g = pg * PPG + it;
    float yk0[K_NN];
    float u0 = 0.f, v0 = 0.f;
    #pragma unroll
    for (int k = 0; k < K_NN; ++k) yk0[k] = 0.f;
    const float* W0 = W + (size_t)o0 * (2 * C);
    #pragma unroll
    for (int c = 0; c < C; ++c) {
      const float wl = W0[c], whv = W0[C + c], ccv = pts[g][0][c];
      u0 += wl * ccv; v0 += whv * ccv;
      #pragma unroll
      for (int k = 0; k < K_NN; ++k) yk0[k] += wl * pts[g][k + 1][c];
    }
    const int n = p0 + g - b * Npts;
    const size_t obase = ((size_t)b * Npts + n) * O;
    const float base = v0 - u0;
    float vmx = -FLT_MAX, vmn = FLT_MAX;
    #pragma unroll
    for (int k = 0; k < K_NN; ++k) {
      float y = yk0[k] + base;
      ls0 += y; lq0 += y * y;
      vmx = fmaxf(vmx, y); vmn = fminf(vmn, y);
    }
    mx[obase + o0] = vmx; mn[obase + o0] = vmn;
  }

  shps[pg][o0] = ls0; shpq[pg][o0] = lq0;
  __syncthreads();
  if (t < O) {
    float s = 0.f, qq = 0.f;
    #pragma unroll
    for (int i = 0; i < NPG; ++i) { s += shps[i][t]; qq += shpq[i][t]; }
    psum[(size_t)blockIdx.x * O + t] = s;
    psq [(size_t)blockIdx.x * O + t] = qq;
  }
}

// ------------------------------------------------- two-stage BN stats
template<int O, int NBLK>
__global__ __launch_bounds__(256) void stats_part(const float* __restrict__ psum,
    const float* __restrict__ psq, double* __restrict__ pp, double* __restrict__ pq) {
  constexpr int NS = 16;
  constexpr int SL = NBLK / NS;
  const int l = threadIdx.x & 63, w = threadIdx.x >> 6;
  const int os = blockIdx.x % (O / 64), sl = blockIdx.x / (O / 64);
  const int o = os * 64 + l;
  double s = 0.0, ss = 0.0;
  for (int i = sl * SL + w; i < (sl + 1) * SL; i += 4) {
    s  += (double)psum[(size_t)i * O + o];
    ss += (double)psq [(size_t)i * O + o];
  }
  __shared__ double sh[2][4][64];
  sh[0][w][l] = s; sh[1][w][l] = ss;
  __syncthreads();
  if (w == 0) {
    s  = sh[0][0][l] + sh[0][1][l] + sh[0][2][l] + sh[0][3][l];
    ss = sh[1][0][l] + sh[1][1][l] + sh[1][2][l] + sh[1][3][l];
    pp[(size_t)sl * O + o] = s;
    pq[(size_t)sl * O + o] = ss;
  }
}

template<int O>
__global__ __launch_bounds__(64) void stats_final(const double* __restrict__ pp,
    const double* __restrict__ pq,
    const float* __restrict__ gamma, const float* __restrict__ beta,
    float* __restrict__ scale, float* __restrict__ bias) {
  const int o = blockIdx.x * 64 + threadIdx.x;
  double s = 0.0, ss = 0.0;
  #pragma unroll
  for (int sl = 0; sl < 16; ++sl) { s += pp[(size_t)sl * O + o]; ss += pq[(size_t)sl * O + o]; }
  double cnt = (double)Bsz * Npts * K_NN;
  double m = s / cnt;
  double var = ss / cnt - m * m;
  float g = gamma[o];
  float sc = g * rsqrtf((float)var + EPS);
  scale[o] = sc;
  bias[o] = beta[o] - (float)m * sc;
}

// ------------------------------------------------- reset pooled accumulators
__global__ __launch_bounds__(256) void reset_pool(unsigned* __restrict__ pooled) {
  int i = blockIdx.x * 256 + threadIdx.x;
  if (i < Bsz * 448) pooled[i] = 0u;   // 0 < encf(f) for all finite f
}

// ------------------------------------------------- normalize + lrelu + pool + bf16 split
template<int O, int COFF, bool WNC>
__global__ __launch_bounds__(256) void apply_kernel(const float* __restrict__ mx,
    const float* __restrict__ mn, const float* __restrict__ scale,
    const float* __restrict__ bias, float* __restrict__ xnc,
    unsigned short* __restrict__ xh, unsigned short* __restrict__ xl,
    unsigned* __restrict__ pooled) {
  constexpr int OT = O / 64;
  constexpr int NCH = Npts / 256;
  const int bid = blockIdx.x;
  const int nchunk = bid % NCH;
  const int ot = (bid / NCH) % OT;
  const int b = bid / (NCH * OT);
  const int l = threadIdx.x & 63, w = threadIdx.x >> 6;
  const int o = ot * 64 + l;
  const float sc = scale[o], bs = bias[o];
  const bool pos = (sc >= 0.f);
  float vmax = -FLT_MAX;
  const int n0 = nchunk * 256;
  for (int i = 0; i < 64; ++i) {
    int n = n0 + w + i * 4;
    size_t ix = ((size_t)b * Npts + n) * O + o;
    float raw = pos ? mx[ix] : mn[ix];   // max for +scale, min for -scale
    float y = raw * sc + bs;
    y = (y >= 0.f) ? y : SLOPE * y;
    if constexpr (WNC) {
      xnc[ix] = y;
      unsigned short h = f2bf(y);
      xh[ix] = h;
      xl[ix] = f2bf(y - bf2f(h));
    }
    vmax = fmaxf(vmax, y);
  }
  __shared__ float sh[4][64];
  sh[w][l] = vmax;
  __syncthreads();
  if (w == 0) {
    float m = fmaxf(fmaxf(sh[0][l], sh[1][l]), fmaxf(sh[2][l], sh[3][l]));
    atomicMax(pooled + b * 448 + COFF + o, encf(m));
  }
}

// ------------------------------------------------- FC layers
template<int CIN, bool LRELU, bool DECODE>
__global__ __launch_bounds__(64) void fc_kernel(const void* __restrict__ inv,
    const float* __restrict__ Wt, float* __restrict__ out, int JO) {
  int j = blockIdx.x;
  const float* wr = Wt + (size_t)j * CIN;
  float acc[Bsz];
  #pragma unroll
  for (int b = 0; b < Bsz; ++b) acc[b] = 0.f;
  for (int c = threadIdx.x; c < CIN; c += 64) {
    float wv = wr[c];
    #pragma unroll
    for (int b = 0; b < Bsz; ++b) {
      float x;
      if constexpr (DECODE) x = decf(((const unsigned*)inv)[b * CIN + c]);
      else                  x = ((const float*)inv)[b * CIN + c];
      acc[b] += x * wv;
    }
  }
  #pragma unroll
  for (int b = 0; b < Bsz; ++b) {
    float v = acc[b];
    #pragma unroll
    for (int w = 32; w > 0; w >>= 1) v += __shfl_down(v, w);
    if (threadIdx.x == 0) {
      if (LRELU) v = (v >= 0.f) ? v : SLOPE * v;
      out[b * JO + j] = v;
    }
  }
}

// ================================================================ launch
extern "C" void kernel_launch(void* const* d_in, const int* in_sizes, int n_in,
                              void* d_out, int out_size, void* d_ws, size_t ws_size,
                              hipStream_t stream) {
  const float* x   = (const float*)d_in[0];
  const float* W1  = (const float*)d_in[1];
  const float* g1  = (const float*)d_in[2];
  const float* b1  = (const float*)d_in[3];
  const float* W2  = (const float*)d_in[4];
  const float* g2  = (const float*)d_in[5];
  const float* b2  = (const float*)d_in[6];
  const float* W3  = (const float*)d_in[7];
  const float* g3  = (const float*)d_in[8];
  const float* b3  = (const float*)d_in[9];
  const float* L1  = (const float*)d_in[10];
  const float* L2  = (const float*)d_in[11];
  float* out = (float*)d_out;

  float* ws = (float*)d_ws;
  size_t off = 0;
  float* sq    = ws + off; off += BN;
  int*   idxb  = (int*)(ws + off); off += (size_t)BN * K_NN;
  float* mx    = ws + off; off += (size_t)BN * 256;
  float* mn    = ws + off; off += (size_t)BN * 256;
  float* Z     = ws + off; off += (size_t)BN * 256;          // 16.8MB (2-pass for L3)
  float* psum  = ws + off; off += (size_t)2048 * 256;
  float* psq   = ws + off; off += (size_t)2048 * 256;
  off = (off + 1) & ~(size_t)1;   // 8B align for doubles
  double* pp   = (double*)(ws + off); off += 16 * 256 * 2;
  double* pq   = (double*)(ws + off); off += 16 * 256 * 2;
  float* scale = ws + off; off += 256;
  float* bias  = ws + off; off += 256;
  float* x1nc  = ws + off; off += (size_t)BN * 64;
  float* x2nc  = ws + off; off += (size_t)BN * 128;
  unsigned short* xh1 = (unsigned short*)(ws + off); off += (size_t)BN * 64 / 2;
  unsigned short* xl1 = (unsigned short*)(ws + off); off += (size_t)BN * 64 / 2;
  unsigned short* xh2 = (unsigned short*)(ws + off); off += (size_t)BN * 128 / 2;
  unsigned short* xl2 = (unsigned short*)(ws + off); off += (size_t)BN * 128 / 2;
  unsigned* pooled = (unsigned*)(ws + off); off += Bsz * 448;
  float* h     = ws + off; off += Bsz * 1024;
  unsigned short* wch2 = (unsigned short*)(ws + off); off += 256 * 64 / 2;
  unsigned short* wcl2 = (unsigned short*)(ws + off); off += 256 * 64 / 2;
  unsigned short* wch3 = (unsigned short*)(ws + off); off += 512 * 128 / 2;
  unsigned short* wcl3 = (unsigned short*)(ws + off); off += 512 * 128 / 2;
  // layer-1 knn partial lists overlay mx/mn (disjoint lifetimes)
  float* pval = mx;
  int*   pidx = (int*)mn;

  reset_pool<<<14, 256, 0, stream>>>(pooled);
  prep_w<64, 128><<<(2 * 128 * 64 + 255) / 256, 256, 0, stream>>>(W2, wch2, wcl2);
  prep_w<128, 256><<<(2 * 256 * 128 + 255) / 256, 256, 0, stream>>>(W3, wch3, wcl3);

  // ---- edge block 1: C=3 -> O=64 (fp32 vector knn + conv)
  sq_kernel<3><<<64, 256, 0, stream>>>(x, sq);
  knn_part<3, 64><<<(BN / 256) * NQ, 256, 0, stream>>>(x, sq, pval, pidx);
  knn_merge<<<64, 256, 0, stream>>>(pval, pidx, idxb);
  edge_kernel<3, 64, 16, 4, 1><<<BN / 16, 256, 0, stream>>>(x, idxb, W1, mx, mn, psum, psq);
  stats_part<64, 1024><<<16, 256, 0, stream>>>(psum, psq, pp, pq);
  stats_final<64><<<1, 64, 0, stream>>>(pp, pq, g1, b1, scale, bias);
  apply_kernel<64, 0, true><<<64, 256, 0, stream>>>(mx, mn, scale, bias, x1nc, xh1, xl1, pooled);

  // ---- edge block 2: C=64 -> O=128 (fused knn + Z-GEMM + gather-reduce)
  sq_kernel<64><<<64, 256, 0, stream>>>(x1nc, sq);
  knn_fused<64><<<Bsz * 128, 256, 0, stream>>>(xh1, xl1, sq, idxb);
  zgemm<64, 256><<<(BN / 64) * 4, 256, 0, stream>>>(xh1, xl1, wch2, wcl2, Z, 0);
  nbr_reduce<128, 16><<<BN / 16, 256, 0, stream>>>(Z, idxb, mx, mn, psum, psq, 0);
  stats_part<128, 1024><<<32, 256, 0, stream>>>(psum, psq, pp, pq);
  stats_final<128><<<2, 64, 0, stream>>>(pp, pq, g2, b2, scale, bias);
  apply_kernel<128, 64, true><<<128, 256, 0, stream>>>(mx, mn, scale, bias, x2nc, xh2, xl2, pooled);

  // ---- edge block 3: C=128 -> O=256 (fused knn + 2-pass Z-GEMM + gather-reduce)
  sq_kernel<128><<<64, 256, 0, stream>>>(x2nc, sq);
  knn_fused<128><<<Bsz * 128, 256, 0, stream>>>(xh2, xl2, sq, idxb);
  for (int pass = 0; pass < 2; ++pass) {
    const int r0 = pass * (BN / 2);
    zgemm<128, 512><<<(BN / 2 / 64) * 8, 256, 0, stream>>>(xh2, xl2, wch3, wcl3, Z, r0);
    nbr_reduce<256, 8><<<BN / 2 / 8, 256, 0, stream>>>(Z, idxb, mx, mn,
        psum + (size_t)pass * 1024 * 256, psq + (size_t)pass * 1024 * 256, r0);
  }
  stats_part<256, 2048><<<64, 256, 0, stream>>>(psum, psq, pp, pq);
  stats_final<256><<<4, 64, 0, stream>>>(pp, pq, g3, b3, scale, bias);
  apply_kernel<256, 192, false><<<256, 256, 0, stream>>>(mx, mn, scale, bias, nullptr, nullptr, nullptr, pooled);

  // ---- head
  fc_kernel<448, true, true><<<1024, 64, 0, stream>>>(pooled, L1, h, 1024);
  fc_kernel<1024, false, false><<<2500, 64, 0, stream>>>(h, L2, out, 2500);
}